// Round 4
// baseline (230.484 us; speedup 1.0000x reference)
//
#include <hip/hip_runtime.h>
#include <cstdint>

#define CONF_THRES 0.25f
#define IOU_THRES  0.45f
#define MAX_DET    300
#define K_TOP      8192
#define NA         102000
#define NCLS       80
#define ROWLEN     85
#define CAP        32640
#define NPLANE     32
#define NBINS      16384        // scores < 1.0 -> sb>>16 < 0x3f80 < 16384
#define WIN        512
#define NWIN       (K_TOP / WIN)
#define SSTR       9            // LDS row stride in u64 (pad 8->9: bank spread)

typedef unsigned long long u64;
typedef unsigned int u32;

// ---------------- kernel 0: zero meta+remw+sorted + rankArr + hist planes ---------
// Replaces all hipMemsetAsync fills (round-1 profile: fillBufferAligned ran 43.8us
// writing 268MB for an 8MB request). rankArr now lives in its own (non-aliased)
// region so it can be zeroed up-front too.
__global__ __launch_bounds__(256) void zero_kernel(uint4* __restrict__ a,
        uint4* __restrict__ r, uint4* __restrict__ b) {
    int i = blockIdx.x * 256 + threadIdx.x;          // grid 256 -> 65536 threads
    uint4 z = make_uint4(0u, 0u, 0u, 0u);
    if (i < 4164) a[i] = z;                          // meta+remw+sorted = 66624 B
    if (i < 8160) r[i] = z;                          // rankArr = 130560 B
    b[i] = z;                                        // hist planes: 131072 uint4
    b[i + 65536] = z;
}

// ---------------- kernel 1: wave-per-anchor scores -> sortable keys + histogram ----
__global__ __launch_bounds__(256) void score_key_kernel(const float* __restrict__ preds,
        u64* __restrict__ keys, u32* __restrict__ histP) {
#pragma clang fp contract(off)
    int lane = threadIdx.x & 63;
    int i = blockIdx.x * 4 + (threadIdx.x >> 6);     // 4 waves/block, 1 anchor/wave
    if (i >= NA) return;
    const float* p = preds + (size_t)i * ROWLEN;
    float v0 = p[lane];                               // offsets 0..63
    float v1 = (lane < ROWLEN - 64) ? p[64 + lane] : 0.0f; // offsets 64..84
    float obj = __shfl(v0, 4);
    float m = (lane >= 5) ? v0 : 0.0f;                // classes 0..58 (scores >= 0)
    m = fmaxf(m, (lane < 21) ? v1 : 0.0f);            // classes 59..79
    for (int off = 32; off; off >>= 1) m = fmaxf(m, __shfl_xor(m, off));
    if (lane == 0) {
        float score = (obj > CONF_THRES) ? m * obj : 0.0f;
        u32 sb = __float_as_uint(score);              // score >= 0: order-preserving bits
        keys[i] = ((u64)sb << 32) | (u32)(~(u32)i);   // tie-break: smaller index wins
        if (sb != 0u)
            atomicAdd(&histP[((u32)blockIdx.x & (NPLANE - 1u)) * NBINS + (sb >> 16)], 1u);
    }
}

// ---------------- kernel 1b: fold 32 histogram planes -> sumhist ----------------
__global__ __launch_bounds__(256) void reduce_hist_kernel(const u32* __restrict__ histP,
        u32* __restrict__ sumhist) {
    int bin = blockIdx.x * 256 + threadIdx.x;         // grid 64 -> 16384 bins
    u32 s = 0;
#pragma unroll
    for (int r = 0; r < NPLANE; ++r) s += histP[r * NBINS + bin];
    sumhist[bin] = s;
}

// ---------------- kernel 2: find threshold bucket for top-K (parallel scan) --------
__global__ __launch_bounds__(1024) void cutoff_kernel(const u32* __restrict__ hist,
        u32* __restrict__ meta) {
    __shared__ u32 suf[1024];
    __shared__ int cbs;
    __shared__ u32 above_s;
    int t = threadIdx.x;
    u32 s = 0;
    const u32* hb = hist + t * 16;                    // 1024 chunks x 16 bins
    for (int b = 0; b < 16; ++b) s += hb[b];
    suf[t] = s;
    if (t == 0) { cbs = -1; above_s = 0; }
    __syncthreads();
    for (int off = 1; off < 1024; off <<= 1) {
        u32 add = (t + off < 1024) ? suf[t + off] : 0u;
        __syncthreads();
        suf[t] += add;
        __syncthreads();
    }
    u32 st = suf[t];
    u32 stn = (t < 1023) ? suf[t + 1] : 0u;
    if (st >= (u32)K_TOP && stn < (u32)K_TOP) {       // at most one thread
        cbs = t;
        above_s = stn;                                 // sum of chunks above cb
    }
    __syncthreads();
    int cb = cbs;
    if (t < 64) {                                      // wave 0 does the fine pass
        u32 thresh = 0;
        if (cb >= 0) {
            u32 above = above_s;
            u32 v = (t < 16) ? hist[cb * 16 + t] : 0u;
            for (int off = 1; off < 64; off <<= 1) {
                u32 o = __shfl_down(v, off);
                if (t + off < 64) v += o;
            }
            u64 bal = __ballot(v + above >= (u32)K_TOP);
            int bstar = 63 - __builtin_clzll((unsigned long long)bal);
            thresh = ((u32)(cb * 16 + bstar)) << 16;
        }
        if (t == 0) meta[1] = thresh;                  // meta[0] zeroed by zero_kernel
    }
}

// ---------------- kernel 3: compact candidates above threshold ----------------
__global__ __launch_bounds__(256) void compact_kernel(const u64* __restrict__ keys,
        u32* __restrict__ meta, u64* __restrict__ comp) {
    __shared__ u32 woff[4];
    __shared__ u32 bbase;
    int i = blockIdx.x * 256 + threadIdx.x;
    int wid = threadIdx.x >> 6, lane = threadIdx.x & 63;
    u64 key = (i < NA) ? keys[i] : 0ull;
    u32 sb = (u32)(key >> 32);
    u32 th = meta[1];
    bool take = (i < NA) && (sb != 0u) && (sb >= th);
    u64 bal = __ballot(take);
    if (lane == 0) woff[wid] = (u32)__popcll(bal);
    __syncthreads();
    if (threadIdx.x == 0) {
        u32 t0 = woff[0], t1 = woff[1], t2 = woff[2], t3 = woff[3];
        bbase = atomicAdd(&meta[0], t0 + t1 + t2 + t3);
        woff[0] = 0; woff[1] = t0; woff[2] = t0 + t1; woff[3] = t0 + t1 + t2;
    }
    __syncthreads();
    if (take) {
        u32 pos = bbase + woff[wid] + (u32)__popcll(bal & ((1ull << lane) - 1ull));
        if (pos < CAP) comp[pos] = key;
    }
}

// ---------------- kernel 4a: 2-D partial rank-by-counting ----------------
__global__ __launch_bounds__(256) void rank_partial_kernel(const u64* __restrict__ comp,
        const u32* __restrict__ meta, u32* __restrict__ rankArr) {
    __shared__ u64 tile[1024];
    u32 cnt = meta[0];
    int n = (int)(cnt < (u32)CAP ? cnt : (u32)CAP);
    int i0 = blockIdx.x * 256;
    int j0 = blockIdx.y * 1024;
    if (i0 >= n || j0 >= n) return;                  // uniform early exit
    int lim = n - j0; if (lim > 1024) lim = 1024;
    for (int k = threadIdx.x; k < 1024; k += 256)
        tile[k] = (k < lim) ? comp[j0 + k] : 0ull;
    __syncthreads();
    int i = i0 + threadIdx.x;
    if (i < n) {
        u64 key = comp[i];
        u32 r = 0;
#pragma unroll 8
        for (int j = 0; j < 1024; ++j) r += (tile[j] > key) ? 1u : 0u;
        atomicAdd(&rankArr[i], r);
    }
}

// ---------------- kernel 4b: scatter keys to their rank ----------------
__global__ __launch_bounds__(256) void scatter_kernel(const u64* __restrict__ comp,
        const u32* __restrict__ meta, const u32* __restrict__ rankArr,
        u64* __restrict__ sorted) {
    u32 cnt = meta[0];
    int n = (int)(cnt < (u32)CAP ? cnt : (u32)CAP);
    int i = blockIdx.x * 256 + threadIdx.x;
    if (i < n) {
        u32 r = rankArr[i];
        if (r < (u32)K_TOP) sorted[r] = comp[i];     // keys unique -> permutation
    }
}

// ---------------- kernel 5: wave-per-anchor gather of boxes/classes/scores ---------
// Also emits per-candidate area (same f32 values & formula as reference ->
// bit-identical) for the mask kernel's register row path.
__global__ __launch_bounds__(256) void gather_kernel(const u64* __restrict__ sorted,
        const float* __restrict__ preds, float* __restrict__ boxes,
        float* __restrict__ scores, float* __restrict__ classes,
        float* __restrict__ areas) {
#pragma clang fp contract(off)
    int lane = threadIdx.x & 63;
    int i = blockIdx.x * 4 + (threadIdx.x >> 6);     // i in [0, 8192)
    u64 key = sorted[i];
    u32 sb = (u32)(key >> 32);
    float score = __uint_as_float(sb);
    if (score > 0.0f) {                               // uniform across the wave
        u32 idx = ~(u32)(key & 0xffffffffull);
        const float* p = preds + (size_t)idx * ROWLEN;
        float v0 = p[lane];
        float v1 = (lane < ROWLEN - 64) ? p[64 + lane] : 0.0f;
        float obj = __shfl(v0, 4);
        u64 kb = 0;
        if (lane >= 5) {
            float q = v0 * obj;                       // class lane-5
            kb = ((u64)__float_as_uint(q) << 8) | (u32)(255 - (lane - 5));
        }
        if (lane < 21) {
            float q = v1 * obj;                       // class 59+lane
            u64 kb2 = ((u64)__float_as_uint(q) << 8) | (u32)(255 - (59 + lane));
            if (kb2 > kb) kb = kb2;
        }
        for (int off = 32; off; off >>= 1) {
            u64 o = __shfl_xor(kb, off);
            if (o > kb) kb = o;
        }
        u32 cls = 255u - (u32)(kb & 0xffull);
        float x = __shfl(v0, 0), y = __shfl(v0, 1);
        float w = __shfl(v0, 2), h = __shfl(v0, 3);
        if (lane == 0) {
            float ymin = y - h * 0.5f, xmin = x - w * 0.5f;
            float ymax = y + h * 0.5f, xmax = x + w * 0.5f;
            boxes[i * 4 + 0] = ymin;
            boxes[i * 4 + 1] = xmin;
            boxes[i * 4 + 2] = ymax;
            boxes[i * 4 + 3] = xmax;
            scores[i] = score;
            classes[i] = (float)cls;
            areas[i] = (ymax - ymin) * (xmax - xmin);
        }
    } else if (lane == 0) {
        boxes[i * 4 + 0] = 0.0f; boxes[i * 4 + 1] = 0.0f;
        boxes[i * 4 + 2] = 0.0f; boxes[i * 4 + 3] = 0.0f;
        scores[i] = 0.0f;
        classes[i] = 0.0f;
        areas[i] = 0.0f;
    }
}

// ---------------- kernel 6: full suppression bitmask (iou > thres, j > i) ----------
// Round-13/14 rewrite. Round-2 post-mortem: wave-uniform row loads DID scalarize
// (SGPR=80) but put 128 s_loads in the inner loop -> lgkmcnt stalls every 8 rows
// (VALUBusy 50%, 54us). Fix: inner loop is now MEMORY-FREE. Each lane loads its
// own row's box/area once; the fully-unrolled row loop pulls row rr's data from
// wave registers via v_readlane (compile-time lane -> SGPR result, feeds
// v_max_f32 v,s,v within the 1-SGPR/op limit). The __ballot result lands in the
// owning lane via a lane==rr select (v_cmp + cndmask; no writelane builtin on
// this toolchain). Diagonal handling is a per-iteration SALU-only mask -> one
// unified path for all tiles. ~35 VALU/iter, zero loads. Below-diagonal tiles
// skipped entirely (those words are never read by the scan; verified by round-2
// passing with stale data there). IoU order + IEEE divide unchanged.
__global__ __launch_bounds__(256) void mask_kernel(const float* __restrict__ boxes,
        const float* __restrict__ areas, u64* __restrict__ mask) {
#pragma clang fp contract(off)
    int cx = blockIdx.x;                 // col tile: 256 cols = words [cx*4, cx*4+4)
    int ry = blockIdx.y;                 // row tile: rows [ry*64, ry*64+64)
    if (cx < (ry >> 2)) return;          // fully below diagonal: never read
    __shared__ u64 st[64 * 5];           // [row][word], stride 5 (bank spread)
    int wv = threadIdx.x >> 6, lane = threadIdx.x & 63;
    int jw = cx * 4 + wv;                // this wave's column word
    int j  = jw * 64 + lane;             // this lane's column
    int r0 = ry * 64;
    int jb = jw * 64;                    // first column of this word
    float4 bj = ((const float4*)boxes)[j];
    float aj = areas[j];
    float4 bi = ((const float4*)boxes)[r0 + lane];   // this lane's ROW data
    float ai = areas[r0 + lane];
    u64 myword = 0;
#pragma unroll
    for (int rr = 0; rr < 64; ++rr) {
        float sx = __int_as_float(__builtin_amdgcn_readlane(__float_as_int(bi.x), rr));
        float sy = __int_as_float(__builtin_amdgcn_readlane(__float_as_int(bi.y), rr));
        float sz = __int_as_float(__builtin_amdgcn_readlane(__float_as_int(bi.z), rr));
        float sw = __int_as_float(__builtin_amdgcn_readlane(__float_as_int(bi.w), rr));
        float sa = __int_as_float(__builtin_amdgcn_readlane(__float_as_int(ai), rr));
        float ty = fmaxf(sx, bj.x);
        float tx = fmaxf(sy, bj.y);
        float by = fminf(sz, bj.z);
        float bx = fminf(sw, bj.w);
        float inter = fmaxf(by - ty, 0.0f) * fmaxf(bx - tx, 0.0f);
        float uni = (sa + aj) - inter;
        float iou = inter / (uni + 1e-9f);
        u64 bal = __ballot(iou > IOU_THRES);
        int d = (r0 + rr) - jb;                       // bits valid for lane > d
        u64 vm = (d < 0) ? ~0ull : ((d >= 63) ? 0ull : (~0ull << (d + 1)));
        bal &= vm;                                    // SALU only
        if (lane == rr) myword = bal;                 // v_cmp + 2 cndmask
    }
    st[lane * 5 + wv] = myword;                       // lane's row word jw
    __syncthreads();
    int t = threadIdx.x;
    mask[(size_t)(r0 + (t >> 2)) * 128 + cx * 4 + (t & 3)] = st[(t >> 2) * 5 + (t & 3)];
}

// ---------------- kernel 6b: validity words (rem init) for the scan ----------------
__global__ __launch_bounds__(256) void valid_kernel(const float* __restrict__ scores,
        u64* __restrict__ remw) {
    int w = blockIdx.x * 4 + (threadIdx.x >> 6);      // 128 waves over 32 blocks
    int lane = threadIdx.x & 63;
    u64 b = __ballot(scores[w * 64 + lane] > 0.0f);
    if (lane == 0) remw[w] = b;
}

// ---------------- kernel 7: single-wave greedy scan, 16 LDS windows, no fallback ---
__device__ __forceinline__ u64 rfl64(u64 v) {
    u32 lo = (u32)__builtin_amdgcn_readfirstlane((int)(u32)v);
    u32 hi = (u32)__builtin_amdgcn_readfirstlane((int)(u32)(v >> 32));
    return ((u64)hi << 32) | lo;
}

__device__ __forceinline__ u64 bcast64(u64 v, int srclane) {
    u32 lo = (u32)__builtin_amdgcn_readlane((int)(u32)v, srclane);
    u32 hi = (u32)__builtin_amdgcn_readlane((int)(u32)(v >> 32), srclane);
    return ((u64)hi << 32) | lo;
}

__device__ __forceinline__ u64 shfl_xor64(u64 v, int m) {
    u32 lo = __shfl_xor((u32)v, m, 64);
    u32 hi = __shfl_xor((u32)(v >> 32), m, 64);
    return ((u64)hi << 32) | lo;
}

__global__ __launch_bounds__(64) void nms_scan_kernel(const u64* __restrict__ mask,
        const u64* __restrict__ remw, const float* __restrict__ boxes,
        const float* __restrict__ scores, const float* __restrict__ classes,
        float* __restrict__ out) {
    __shared__ u64 sub[WIN * SSTR];                   // 36 KB padded window submatrix
    __shared__ u32 ki[MAX_DET + 8];                   // kept indices (ascending)
    int lane = threadIdx.x;                           // exactly one wave
    int n = 0;
    for (int win = 0; win < NWIN && n < MAX_DET; ++win) {
        int rbase = win * WIN;
        __syncthreads();                              // prev window's sub reads done
        // stage diag window: rows [rbase, rbase+WIN) x words [win*8, win*8+8)
#pragma unroll 8
        for (int it = 0; it < 32; ++it) {
            int idx = it * 64 + lane;                 // uint4 index, 2048 total
            int r = idx >> 2, j = (idx & 3) * 2;
            uint4 v = *(const uint4*)&mask[(size_t)(rbase + r) * 128 + win * 8 + j];
            sub[r * SSTR + j]     = ((u64)v.y << 32) | v.x;
            sub[r * SSTR + j + 1] = ((u64)v.w << 32) | v.z;
        }
        // fold suppression from keeps in earlier windows (parallel over keeps)
        u64 acc[8] = {0, 0, 0, 0, 0, 0, 0, 0};
        for (int m = lane; m < n; m += 64) {
            int k = (int)ki[m];
            const u64* rp = &mask[(size_t)k * 128 + win * 8];
#pragma unroll
            for (int j = 0; j < 8; ++j) acc[j] |= rp[j];
        }
#pragma unroll
        for (int j = 0; j < 8; ++j)
            for (int off = 32; off; off >>= 1) acc[j] |= shfl_xor64(acc[j], off);
        __syncthreads();
        u64 diag[8];
#pragma unroll
        for (int sw = 0; sw < 8; ++sw) diag[sw] = sub[(sw * 64 + lane) * SSTR + sw];
        int n0 = n;
        u64 keptW[8] = {0, 0, 0, 0, 0, 0, 0, 0};
#pragma unroll
        for (int sw = 0; sw < 8; ++sw) {
            if (n < MAX_DET) {
                // suppression from keeps in earlier subwords of THIS window
                u64 acc2 = 0;
#pragma unroll
                for (int wp = 0; wp < 8; ++wp) {
                    if (wp < sw) {
                        if ((keptW[wp] >> lane) & 1ull)
                            acc2 |= sub[(wp * 64 + lane) * SSTR + sw];
                    }
                }
                for (int off = 32; off; off >>= 1) acc2 |= shfl_xor64(acc2, off);
                u64 cur = rfl64(remw[win * 8 + sw]) & ~rfl64(acc[sw]) & ~rfl64(acc2);
                u64 kw = 0;
                while (cur != 0ull && n < MAX_DET) {  // uniform scalar pop chain
                    int b = __ffsll((unsigned long long)cur) - 1;
                    u64 slice = bcast64(diag[sw], b); // row (sw*64+b), word sw
                    kw |= (1ull << b);
                    cur &= ~(slice | (1ull << b));
                    ++n;
                }
                keptW[sw] = kw;
            }
        }
        // append kept indices (parallel; ascending index = greedy order)
        int base = n0;
#pragma unroll
        for (int sw = 0; sw < 8; ++sw) {
            u64 kw = keptW[sw];
            if ((kw >> lane) & 1ull) {
                int rr = (int)__popcll(kw & ((1ull << lane) - 1ull));
                ki[base + rr] = (u32)(rbase + sw * 64 + lane);
            }
            base += (int)__popcll(kw);
        }
        __syncthreads();
    }
    __syncthreads();
    // ---- parallel output phase: lane m handles detection m (5 strided rounds) ----
    for (int m = lane; m < MAX_DET; m += 64) {
        float4 b = make_float4(0.0f, 0.0f, 0.0f, 0.0f);
        float c = 0.0f, s = 0.0f;
        if (m < n) {
            int k = (int)ki[m];
            b = ((const float4*)boxes)[k];
            c = classes[k];
            s = scores[k];
        }
        ((float4*)out)[m] = b;
        out[1200 + m] = c;
        out[1500 + m] = s;
    }
}

// ---------------- launch ----------------
extern "C" void kernel_launch(void* const* d_in, const int* in_sizes, int n_in,
                              void* d_out, int out_size, void* d_ws, size_t ws_size,
                              hipStream_t stream) {
    const float* preds = (const float*)d_in[0];
    char* ws = (char*)d_ws;

    // ws layout (bytes), total 9991104:
    //   [0, 65536)             sumhist     u32[16384]
    //   [65536, 196096)        rankArr     u32[32640] (own region: zeroed up-front)
    //   [262144, 262208)       meta        u32[16]   ([0]=counter, [1]=thresh)
    //   [262208, 263232)       remw        u64[128]
    //   [263232, 328768)       sorted      u64[8192]
    //   [328768, 1144768)      keys        u64[102000] (dead after compact)
    //   [1144768, 1405888)     comp        u64[32640] (dead after scatter;
    //                                      front 32768 B reused as careas)
    //   [1405888, 1536960)     top_boxes   f32[8192*4]
    //   [1536960, 1569728)     top_scores  f32[8192]
    //   [1569728, 1602496)     top_classes f32[8192]
    //   [1602496, 9991104)     mask        u64[8192*128]  (8 MB; front 2 MiB
    //                                      doubles as 32x16384 hist planes earlier)
    u32*   sumhist = (u32*)(ws + 0);
    u32*   rankArr = (u32*)(ws + 65536);
    u32*   meta    = (u32*)(ws + 262144);
    u64*   remw    = (u64*)(ws + 262208);
    u64*   sorted  = (u64*)(ws + 263232);
    u64*   keys    = (u64*)(ws + 328768);
    u64*   comp    = (u64*)(ws + 1144768);
    float* careas  = (float*)(ws + 1144768);         // aliases comp (dead by gather)
    float* tboxes  = (float*)(ws + 1405888);
    float* tscores = (float*)(ws + 1536960);
    float* tclass  = (float*)(ws + 1569728);
    u64*   mask    = (u64*)(ws + 1602496);
    u32*   histP   = (u32*)(ws + 1602496);           // aliases mask region (earlier)
    float* out     = (float*)d_out;

    zero_kernel<<<256, 256, 0, stream>>>((uint4*)(ws + 262144), (uint4*)rankArr,
            (uint4*)histP);
    score_key_kernel<<<(NA + 3) / 4, 256, 0, stream>>>(preds, keys, histP);
    reduce_hist_kernel<<<64, 256, 0, stream>>>(histP, sumhist);
    cutoff_kernel<<<1, 1024, 0, stream>>>(sumhist, meta);
    compact_kernel<<<(NA + 255) / 256, 256, 0, stream>>>(keys, meta, comp);
    rank_partial_kernel<<<dim3((CAP + 255) / 256, (CAP + 1023) / 1024), 256, 0, stream>>>(
            comp, meta, rankArr);
    scatter_kernel<<<(CAP + 255) / 256, 256, 0, stream>>>(comp, meta, rankArr, sorted);
    gather_kernel<<<K_TOP / 4, 256, 0, stream>>>(sorted, preds, tboxes, tscores,
            tclass, careas);
    mask_kernel<<<dim3(32, 128), 256, 0, stream>>>(tboxes, careas, mask);
    valid_kernel<<<32, 256, 0, stream>>>(tscores, remw);
    nms_scan_kernel<<<1, 64, 0, stream>>>(mask, remw, tboxes, tscores, tclass, out);
}

// Round 5
// 196.350 us; speedup vs baseline: 1.1738x; 1.1738x over previous
//
#include <hip/hip_runtime.h>
#include <cstdint>

#define CONF_THRES 0.25f
#define IOU_THRES  0.45f
#define MAX_DET    300
#define K_TOP      8192
#define NA         102000
#define NCLS       80
#define ROWLEN     85
#define CAP        32640
#define NPLANE     32
#define NBINS      16384        // scores < 1.0 -> sb>>16 < 0x3f80 < 16384
#define WIN        512
#define NWIN       (K_TOP / WIN)
#define SSTR       9            // LDS row stride in u64 (pad 8->9: bank spread)

typedef unsigned long long u64;
typedef unsigned int u32;

// ---------------- kernel 0: zero meta+remw+sorted + rankArr + hist planes ---------
// Replaces all hipMemsetAsync fills (round-1 profile: fillBufferAligned ran 43.8us
// writing 268MB for an 8MB request).
__global__ __launch_bounds__(256) void zero_kernel(uint4* __restrict__ a,
        uint4* __restrict__ r, uint4* __restrict__ b) {
    int i = blockIdx.x * 256 + threadIdx.x;          // grid 256 -> 65536 threads
    uint4 z = make_uint4(0u, 0u, 0u, 0u);
    if (i < 4164) a[i] = z;                          // meta+remw+sorted = 66624 B
    if (i < 8160) r[i] = z;                          // rankArr = 130560 B
    b[i] = z;                                        // hist planes: 131072 uint4
    b[i + 65536] = z;
}

// ---------------- kernel 1: wave-per-anchor scores -> sortable keys + histogram ----
__global__ __launch_bounds__(256) void score_key_kernel(const float* __restrict__ preds,
        u64* __restrict__ keys, u32* __restrict__ histP) {
#pragma clang fp contract(off)
    int lane = threadIdx.x & 63;
    int i = blockIdx.x * 4 + (threadIdx.x >> 6);     // 4 waves/block, 1 anchor/wave
    if (i >= NA) return;
    const float* p = preds + (size_t)i * ROWLEN;
    float v0 = p[lane];                               // offsets 0..63
    float v1 = (lane < ROWLEN - 64) ? p[64 + lane] : 0.0f; // offsets 64..84
    float obj = __shfl(v0, 4);
    float m = (lane >= 5) ? v0 : 0.0f;                // classes 0..58 (scores >= 0)
    m = fmaxf(m, (lane < 21) ? v1 : 0.0f);            // classes 59..79
    for (int off = 32; off; off >>= 1) m = fmaxf(m, __shfl_xor(m, off));
    if (lane == 0) {
        float score = (obj > CONF_THRES) ? m * obj : 0.0f;
        u32 sb = __float_as_uint(score);              // score >= 0: order-preserving bits
        keys[i] = ((u64)sb << 32) | (u32)(~(u32)i);   // tie-break: smaller index wins
        if (sb != 0u)
            atomicAdd(&histP[((u32)blockIdx.x & (NPLANE - 1u)) * NBINS + (sb >> 16)], 1u);
    }
}

// ---------------- kernel 1b: fold 32 histogram planes -> sumhist ----------------
__global__ __launch_bounds__(256) void reduce_hist_kernel(const u32* __restrict__ histP,
        u32* __restrict__ sumhist) {
    int bin = blockIdx.x * 256 + threadIdx.x;         // grid 64 -> 16384 bins
    u32 s = 0;
#pragma unroll
    for (int r = 0; r < NPLANE; ++r) s += histP[r * NBINS + bin];
    sumhist[bin] = s;
}

// ---------------- kernel 2: find threshold bucket for top-K (parallel scan) --------
__global__ __launch_bounds__(1024) void cutoff_kernel(const u32* __restrict__ hist,
        u32* __restrict__ meta) {
    __shared__ u32 suf[1024];
    __shared__ int cbs;
    __shared__ u32 above_s;
    int t = threadIdx.x;
    u32 s = 0;
    const u32* hb = hist + t * 16;                    // 1024 chunks x 16 bins
    for (int b = 0; b < 16; ++b) s += hb[b];
    suf[t] = s;
    if (t == 0) { cbs = -1; above_s = 0; }
    __syncthreads();
    for (int off = 1; off < 1024; off <<= 1) {
        u32 add = (t + off < 1024) ? suf[t + off] : 0u;
        __syncthreads();
        suf[t] += add;
        __syncthreads();
    }
    u32 st = suf[t];
    u32 stn = (t < 1023) ? suf[t + 1] : 0u;
    if (st >= (u32)K_TOP && stn < (u32)K_TOP) {       // at most one thread
        cbs = t;
        above_s = stn;                                 // sum of chunks above cb
    }
    __syncthreads();
    int cb = cbs;
    if (t < 64) {                                      // wave 0 does the fine pass
        u32 thresh = 0;
        if (cb >= 0) {
            u32 above = above_s;
            u32 v = (t < 16) ? hist[cb * 16 + t] : 0u;
            for (int off = 1; off < 64; off <<= 1) {
                u32 o = __shfl_down(v, off);
                if (t + off < 64) v += o;
            }
            u64 bal = __ballot(v + above >= (u32)K_TOP);
            int bstar = 63 - __builtin_clzll((unsigned long long)bal);
            thresh = ((u32)(cb * 16 + bstar)) << 16;
        }
        if (t == 0) meta[1] = thresh;                  // meta[0] zeroed by zero_kernel
    }
}

// ---------------- kernel 3: compact candidates above threshold ----------------
__global__ __launch_bounds__(256) void compact_kernel(const u64* __restrict__ keys,
        u32* __restrict__ meta, u64* __restrict__ comp) {
    __shared__ u32 woff[4];
    __shared__ u32 bbase;
    int i = blockIdx.x * 256 + threadIdx.x;
    int wid = threadIdx.x >> 6, lane = threadIdx.x & 63;
    u64 key = (i < NA) ? keys[i] : 0ull;
    u32 sb = (u32)(key >> 32);
    u32 th = meta[1];
    bool take = (i < NA) && (sb != 0u) && (sb >= th);
    u64 bal = __ballot(take);
    if (lane == 0) woff[wid] = (u32)__popcll(bal);
    __syncthreads();
    if (threadIdx.x == 0) {
        u32 t0 = woff[0], t1 = woff[1], t2 = woff[2], t3 = woff[3];
        bbase = atomicAdd(&meta[0], t0 + t1 + t2 + t3);
        woff[0] = 0; woff[1] = t0; woff[2] = t0 + t1; woff[3] = t0 + t1 + t2;
    }
    __syncthreads();
    if (take) {
        u32 pos = bbase + woff[wid] + (u32)__popcll(bal & ((1ull << lane) - 1ull));
        if (pos < CAP) comp[pos] = key;
    }
}

// ---------------- kernel 4a: 2-D partial rank-by-counting ----------------
__global__ __launch_bounds__(256) void rank_partial_kernel(const u64* __restrict__ comp,
        const u32* __restrict__ meta, u32* __restrict__ rankArr) {
    __shared__ u64 tile[1024];
    u32 cnt = meta[0];
    int n = (int)(cnt < (u32)CAP ? cnt : (u32)CAP);
    int i0 = blockIdx.x * 256;
    int j0 = blockIdx.y * 1024;
    if (i0 >= n || j0 >= n) return;                  // uniform early exit
    int lim = n - j0; if (lim > 1024) lim = 1024;
    for (int k = threadIdx.x; k < 1024; k += 256)
        tile[k] = (k < lim) ? comp[j0 + k] : 0ull;
    __syncthreads();
    int i = i0 + threadIdx.x;
    if (i < n) {
        u64 key = comp[i];
        u32 r = 0;
#pragma unroll 8
        for (int j = 0; j < 1024; ++j) r += (tile[j] > key) ? 1u : 0u;
        atomicAdd(&rankArr[i], r);
    }
}

// ---------------- kernel 4b: scatter keys to their rank ----------------
__global__ __launch_bounds__(256) void scatter_kernel(const u64* __restrict__ comp,
        const u32* __restrict__ meta, const u32* __restrict__ rankArr,
        u64* __restrict__ sorted) {
    u32 cnt = meta[0];
    int n = (int)(cnt < (u32)CAP ? cnt : (u32)CAP);
    int i = blockIdx.x * 256 + threadIdx.x;
    if (i < n) {
        u32 r = rankArr[i];
        if (r < (u32)K_TOP) sorted[r] = comp[i];     // keys unique -> permutation
    }
}

// ---------------- kernel 5: wave-per-anchor gather of boxes/classes/scores ---------
// Also emits per-candidate area (same f32 values & formula as reference ->
// bit-identical) for the mask kernel.
__global__ __launch_bounds__(256) void gather_kernel(const u64* __restrict__ sorted,
        const float* __restrict__ preds, float* __restrict__ boxes,
        float* __restrict__ scores, float* __restrict__ classes,
        float* __restrict__ areas) {
#pragma clang fp contract(off)
    int lane = threadIdx.x & 63;
    int i = blockIdx.x * 4 + (threadIdx.x >> 6);     // i in [0, 8192)
    u64 key = sorted[i];
    u32 sb = (u32)(key >> 32);
    float score = __uint_as_float(sb);
    if (score > 0.0f) {                               // uniform across the wave
        u32 idx = ~(u32)(key & 0xffffffffull);
        const float* p = preds + (size_t)idx * ROWLEN;
        float v0 = p[lane];
        float v1 = (lane < ROWLEN - 64) ? p[64 + lane] : 0.0f;
        float obj = __shfl(v0, 4);
        u64 kb = 0;
        if (lane >= 5) {
            float q = v0 * obj;                       // class lane-5
            kb = ((u64)__float_as_uint(q) << 8) | (u32)(255 - (lane - 5));
        }
        if (lane < 21) {
            float q = v1 * obj;                       // class 59+lane
            u64 kb2 = ((u64)__float_as_uint(q) << 8) | (u32)(255 - (59 + lane));
            if (kb2 > kb) kb = kb2;
        }
        for (int off = 32; off; off >>= 1) {
            u64 o = __shfl_xor(kb, off);
            if (o > kb) kb = o;
        }
        u32 cls = 255u - (u32)(kb & 0xffull);
        float x = __shfl(v0, 0), y = __shfl(v0, 1);
        float w = __shfl(v0, 2), h = __shfl(v0, 3);
        if (lane == 0) {
            float ymin = y - h * 0.5f, xmin = x - w * 0.5f;
            float ymax = y + h * 0.5f, xmax = x + w * 0.5f;
            boxes[i * 4 + 0] = ymin;
            boxes[i * 4 + 1] = xmin;
            boxes[i * 4 + 2] = ymax;
            boxes[i * 4 + 3] = xmax;
            scores[i] = score;
            classes[i] = (float)cls;
            areas[i] = (ymax - ymin) * (xmax - xmin);
        }
    } else if (lane == 0) {
        boxes[i * 4 + 0] = 0.0f; boxes[i * 4 + 1] = 0.0f;
        boxes[i * 4 + 2] = 0.0f; boxes[i * 4 + 3] = 0.0f;
        scores[i] = 0.0f;
        classes[i] = 0.0f;
        areas[i] = 0.0f;
    }
}

// ---------------- kernel 6: full suppression bitmask (iou > thres, j > i) ----------
// Round-15: back to the round-0 winning structure (lane=row, column operands via
// LDS broadcast reads, per-lane bit accumulation — round 2/4 showed any s_load /
// readlane in the loop stalls it). Improvements over round 0:
//  * IEEE divide ELIMINATED, provably bit-exactly: fl32(inter/u) > T  <=>
//    inter/u > M with M = T + 2^-26 (T/succ(T) midpoint; midpoint rounds to even
//    = T, so strict). u > 0, so decision == (double)inter > M*(double)u, and M*u
//    is EXACT in f64 (25b x 24b mantissa = 49 <= 53). 2 cvt + f64 mul + f64 cmp
//    replaces ~10-op divide. Branch-free, decision-identical for ALL inputs.
//  * areas precomputed (gather) and staged in LDS.
//  * diagonal masking hoisted out of the loop (per-lane vm applied once;
//    below-diagonal waves skip the loop).
//  * valid_kernel fused in (diag block ballots scores>0 into remw).
// Block = 64 rows x 4 words; below-diag blocks skipped (words never read by the
// scan — verified rounds 2/4). Coalesced flush via LDS transpose (4.2MB WRITE).
__global__ __launch_bounds__(256) void mask_kernel(const float* __restrict__ boxes,
        const float* __restrict__ areas, const float* __restrict__ scores,
        u64* __restrict__ mask, u64* __restrict__ remw) {
#pragma clang fp contract(off)
    int cx = blockIdx.x;                 // col tile: 256 cols = words [cx*4, cx*4+4)
    int ry = blockIdx.y;                 // row tile: rows [ry*64, ry*64+64)
    if (cx < (ry >> 2)) return;          // fully below diagonal: never read
    __shared__ float4 cb[256];           // column boxes
    __shared__ float  ca[256];           // column areas
    __shared__ u64 st[64 * 5];           // [row][word], stride 5 (bank spread)
    int tid = threadIdx.x;
    int wv = tid >> 6, lane = tid & 63;
    int r0 = ry * 64;
    int jw = cx * 4 + wv;                // this wave's column word
    cb[tid] = ((const float4*)boxes)[cx * 256 + tid];   // coalesced col stage
    ca[tid] = areas[cx * 256 + tid];
    if (cx == (ry >> 2) && wv == 0) {    // fused valid: remw[ry]
        u64 b = __ballot(scores[r0 + lane] > 0.0f);
        if (lane == 0) remw[ry] = b;
    }
    __syncthreads();
    u64 myword = 0;
    if (jw >= ry) {                      // below-diag waves: zeros
        float4 bi = ((const float4*)boxes)[r0 + lane];  // this lane's ROW (coalesced)
        float ai = areas[r0 + lane];
        const double Bd = (double)IOU_THRES + 0x1p-26;  // fl32(x)>T <=> x>Bd
        int kb = wv * 64;
#pragma unroll
        for (int k = 0; k < 64; ++k) {
            float4 bj = cb[kb + k];      // all lanes same addr -> LDS broadcast
            float aj = ca[kb + k];
            float ty = fmaxf(bi.x, bj.x);
            float tx = fmaxf(bi.y, bj.y);
            float by = fminf(bi.z, bj.z);
            float bx = fminf(bi.w, bj.w);
            float inter = fmaxf(by - ty, 0.0f) * fmaxf(bx - tx, 0.0f);
            float uni = (ai + aj) - inter;
            float u = uni + 1e-9f;
            bool sup = ((double)inter > Bd * (double)u); // exact == fl32 div > T
            myword |= sup ? (1ull << k) : 0ull;          // k compile-time const
        }
        if (jw == ry)                    // diag word: keep cols j > row only
            myword &= (lane < 63) ? (~0ull << (lane + 1)) : 0ull;
    }
    st[lane * 5 + wv] = myword;          // transpose through LDS for coalesced flush
    __syncthreads();
    mask[(size_t)(r0 + (tid >> 2)) * 128 + cx * 4 + (tid & 3)] =
            st[(tid >> 2) * 5 + (tid & 3)];
}

// ---------------- kernel 7: single-wave greedy scan, 16 LDS windows, no fallback ---
__device__ __forceinline__ u64 rfl64(u64 v) {
    u32 lo = (u32)__builtin_amdgcn_readfirstlane((int)(u32)v);
    u32 hi = (u32)__builtin_amdgcn_readfirstlane((int)(u32)(v >> 32));
    return ((u64)hi << 32) | lo;
}

__device__ __forceinline__ u64 bcast64(u64 v, int srclane) {
    u32 lo = (u32)__builtin_amdgcn_readlane((int)(u32)v, srclane);
    u32 hi = (u32)__builtin_amdgcn_readlane((int)(u32)(v >> 32), srclane);
    return ((u64)hi << 32) | lo;
}

__device__ __forceinline__ u64 shfl_xor64(u64 v, int m) {
    u32 lo = __shfl_xor((u32)v, m, 64);
    u32 hi = __shfl_xor((u32)(v >> 32), m, 64);
    return ((u64)hi << 32) | lo;
}

__global__ __launch_bounds__(64) void nms_scan_kernel(const u64* __restrict__ mask,
        const u64* __restrict__ remw, const float* __restrict__ boxes,
        const float* __restrict__ scores, const float* __restrict__ classes,
        float* __restrict__ out) {
    __shared__ u64 sub[WIN * SSTR];                   // 36 KB padded window submatrix
    __shared__ u32 ki[MAX_DET + 8];                   // kept indices (ascending)
    int lane = threadIdx.x;                           // exactly one wave
    int n = 0;
    for (int win = 0; win < NWIN && n < MAX_DET; ++win) {
        int rbase = win * WIN;
        __syncthreads();                              // prev window's sub reads done
        // stage diag window: rows [rbase, rbase+WIN) x words [win*8, win*8+8)
#pragma unroll 8
        for (int it = 0; it < 32; ++it) {
            int idx = it * 64 + lane;                 // uint4 index, 2048 total
            int r = idx >> 2, j = (idx & 3) * 2;
            uint4 v = *(const uint4*)&mask[(size_t)(rbase + r) * 128 + win * 8 + j];
            sub[r * SSTR + j]     = ((u64)v.y << 32) | v.x;
            sub[r * SSTR + j + 1] = ((u64)v.w << 32) | v.z;
        }
        // fold suppression from keeps in earlier windows (parallel over keeps)
        u64 acc[8] = {0, 0, 0, 0, 0, 0, 0, 0};
        for (int m = lane; m < n; m += 64) {
            int k = (int)ki[m];
            const u64* rp = &mask[(size_t)k * 128 + win * 8];
#pragma unroll
            for (int j = 0; j < 8; ++j) acc[j] |= rp[j];
        }
#pragma unroll
        for (int j = 0; j < 8; ++j)
            for (int off = 32; off; off >>= 1) acc[j] |= shfl_xor64(acc[j], off);
        __syncthreads();
        u64 diag[8];
#pragma unroll
        for (int sw = 0; sw < 8; ++sw) diag[sw] = sub[(sw * 64 + lane) * SSTR + sw];
        int n0 = n;
        u64 keptW[8] = {0, 0, 0, 0, 0, 0, 0, 0};
#pragma unroll
        for (int sw = 0; sw < 8; ++sw) {
            if (n < MAX_DET) {
                // suppression from keeps in earlier subwords of THIS window
                u64 acc2 = 0;
#pragma unroll
                for (int wp = 0; wp < 8; ++wp) {
                    if (wp < sw) {
                        if ((keptW[wp] >> lane) & 1ull)
                            acc2 |= sub[(wp * 64 + lane) * SSTR + sw];
                    }
                }
                for (int off = 32; off; off >>= 1) acc2 |= shfl_xor64(acc2, off);
                u64 cur = rfl64(remw[win * 8 + sw]) & ~rfl64(acc[sw]) & ~rfl64(acc2);
                u64 kw = 0;
                while (cur != 0ull && n < MAX_DET) {  // uniform scalar pop chain
                    int b = __ffsll((unsigned long long)cur) - 1;
                    u64 slice = bcast64(diag[sw], b); // row (sw*64+b), word sw
                    kw |= (1ull << b);
                    cur &= ~(slice | (1ull << b));
                    ++n;
                }
                keptW[sw] = kw;
            }
        }
        // append kept indices (parallel; ascending index = greedy order)
        int base = n0;
#pragma unroll
        for (int sw = 0; sw < 8; ++sw) {
            u64 kw = keptW[sw];
            if ((kw >> lane) & 1ull) {
                int rr = (int)__popcll(kw & ((1ull << lane) - 1ull));
                ki[base + rr] = (u32)(rbase + sw * 64 + lane);
            }
            base += (int)__popcll(kw);
        }
        __syncthreads();
    }
    __syncthreads();
    // ---- parallel output phase: lane m handles detection m (5 strided rounds) ----
    for (int m = lane; m < MAX_DET; m += 64) {
        float4 b = make_float4(0.0f, 0.0f, 0.0f, 0.0f);
        float c = 0.0f, s = 0.0f;
        if (m < n) {
            int k = (int)ki[m];
            b = ((const float4*)boxes)[k];
            c = classes[k];
            s = scores[k];
        }
        ((float4*)out)[m] = b;
        out[1200 + m] = c;
        out[1500 + m] = s;
    }
}

// ---------------- launch ----------------
extern "C" void kernel_launch(void* const* d_in, const int* in_sizes, int n_in,
                              void* d_out, int out_size, void* d_ws, size_t ws_size,
                              hipStream_t stream) {
    const float* preds = (const float*)d_in[0];
    char* ws = (char*)d_ws;

    // ws layout (bytes), total 9991104:
    //   [0, 65536)             sumhist     u32[16384]
    //   [65536, 196096)        rankArr     u32[32640] (own region: zeroed up-front)
    //   [262144, 262208)       meta        u32[16]   ([0]=counter, [1]=thresh)
    //   [262208, 263232)       remw        u64[128]
    //   [263232, 328768)       sorted      u64[8192]
    //   [328768, 1144768)      keys        u64[102000] (dead after compact)
    //   [1144768, 1405888)     comp        u64[32640] (dead after scatter;
    //                                      front 32768 B reused as careas)
    //   [1405888, 1536960)     top_boxes   f32[8192*4]
    //   [1536960, 1569728)     top_scores  f32[8192]
    //   [1569728, 1602496)     top_classes f32[8192]
    //   [1602496, 9991104)     mask        u64[8192*128]  (8 MB; front 2 MiB
    //                                      doubles as 32x16384 hist planes earlier)
    u32*   sumhist = (u32*)(ws + 0);
    u32*   rankArr = (u32*)(ws + 65536);
    u32*   meta    = (u32*)(ws + 262144);
    u64*   remw    = (u64*)(ws + 262208);
    u64*   sorted  = (u64*)(ws + 263232);
    u64*   keys    = (u64*)(ws + 328768);
    u64*   comp    = (u64*)(ws + 1144768);
    float* careas  = (float*)(ws + 1144768);         // aliases comp (dead by gather)
    float* tboxes  = (float*)(ws + 1405888);
    float* tscores = (float*)(ws + 1536960);
    float* tclass  = (float*)(ws + 1569728);
    u64*   mask    = (u64*)(ws + 1602496);
    u32*   histP   = (u32*)(ws + 1602496);           // aliases mask region (earlier)
    float* out     = (float*)d_out;

    zero_kernel<<<256, 256, 0, stream>>>((uint4*)(ws + 262144), (uint4*)rankArr,
            (uint4*)histP);
    score_key_kernel<<<(NA + 3) / 4, 256, 0, stream>>>(preds, keys, histP);
    reduce_hist_kernel<<<64, 256, 0, stream>>>(histP, sumhist);
    cutoff_kernel<<<1, 1024, 0, stream>>>(sumhist, meta);
    compact_kernel<<<(NA + 255) / 256, 256, 0, stream>>>(keys, meta, comp);
    rank_partial_kernel<<<dim3((CAP + 255) / 256, (CAP + 1023) / 1024), 256, 0, stream>>>(
            comp, meta, rankArr);
    scatter_kernel<<<(CAP + 255) / 256, 256, 0, stream>>>(comp, meta, rankArr, sorted);
    gather_kernel<<<K_TOP / 4, 256, 0, stream>>>(sorted, preds, tboxes, tscores,
            tclass, careas);
    mask_kernel<<<dim3(32, 128), 256, 0, stream>>>(tboxes, careas, tscores, mask, remw);
    nms_scan_kernel<<<1, 64, 0, stream>>>(mask, remw, tboxes, tscores, tclass, out);
}

// Round 6
// 193.298 us; speedup vs baseline: 1.1924x; 1.0158x over previous
//
#include <hip/hip_runtime.h>
#include <cstdint>

#define CONF_THRES 0.25f
#define IOU_THRES  0.45f
#define MAX_DET    300
#define K_TOP      8192
#define NA         102000
#define NCLS       80
#define ROWLEN     85
#define CAP        32640
#define NPLANE     8
#define NBINS      16384        // scores < 1.0 -> sb>>16 < 0x3f80 < 16384
#define WIN        512
#define NWIN       (K_TOP / WIN)
#define SSTR       9            // LDS row stride in u64 (pad 8->9: bank spread)

typedef unsigned long long u64;
typedef unsigned int u32;

// ---------------- kernel 0: zero meta+remw+sorted + rankArr + hist planes ---------
// Replaces all hipMemsetAsync fills. 8 planes x 64KB = 512KB now.
__global__ __launch_bounds__(256) void zero_kernel(uint4* __restrict__ a,
        uint4* __restrict__ r, uint4* __restrict__ b) {
    int i = blockIdx.x * 256 + threadIdx.x;          // grid 128 -> 32768 threads
    uint4 z = make_uint4(0u, 0u, 0u, 0u);
    if (i < 4164) a[i] = z;                          // meta+remw+sorted = 66624 B
    if (i < 8160) r[i] = z;                          // rankArr = 130560 B
    b[i] = z;                                        // hist planes: 32768 uint4
}

// ---------------- kernel 1: wave-per-anchor scores -> sortable keys + histogram ----
__global__ __launch_bounds__(256) void score_key_kernel(const float* __restrict__ preds,
        u64* __restrict__ keys, u32* __restrict__ histP) {
#pragma clang fp contract(off)
    int lane = threadIdx.x & 63;
    int i = blockIdx.x * 4 + (threadIdx.x >> 6);     // 4 waves/block, 1 anchor/wave
    if (i >= NA) return;
    const float* p = preds + (size_t)i * ROWLEN;
    float v0 = p[lane];                               // offsets 0..63
    float v1 = (lane < ROWLEN - 64) ? p[64 + lane] : 0.0f; // offsets 64..84
    float obj = __shfl(v0, 4);
    float m = (lane >= 5) ? v0 : 0.0f;                // classes 0..58 (scores >= 0)
    m = fmaxf(m, (lane < 21) ? v1 : 0.0f);            // classes 59..79
    for (int off = 32; off; off >>= 1) m = fmaxf(m, __shfl_xor(m, off));
    if (lane == 0) {
        float score = (obj > CONF_THRES) ? m * obj : 0.0f;
        u32 sb = __float_as_uint(score);              // score >= 0: order-preserving bits
        keys[i] = ((u64)sb << 32) | (u32)(~(u32)i);   // tie-break: smaller index wins
        if (sb != 0u)
            atomicAdd(&histP[((u32)blockIdx.x & (NPLANE - 1u)) * NBINS + (sb >> 16)], 1u);
    }
}

// ---------------- kernel 1b: fold 8 histogram planes -> sumhist ----------------
__global__ __launch_bounds__(256) void reduce_hist_kernel(const u32* __restrict__ histP,
        u32* __restrict__ sumhist) {
    int bin = blockIdx.x * 256 + threadIdx.x;         // grid 64 -> 16384 bins
    u32 s = 0;
#pragma unroll
    for (int r = 0; r < NPLANE; ++r) s += histP[r * NBINS + bin];
    sumhist[bin] = s;
}

// ---------------- kernel 2: find threshold bucket for top-K (parallel scan) --------
__global__ __launch_bounds__(1024) void cutoff_kernel(const u32* __restrict__ hist,
        u32* __restrict__ meta) {
    __shared__ u32 suf[1024];
    __shared__ int cbs;
    __shared__ u32 above_s;
    int t = threadIdx.x;
    u32 s = 0;
    const u32* hb = hist + t * 16;                    // 1024 chunks x 16 bins
    for (int b = 0; b < 16; ++b) s += hb[b];
    suf[t] = s;
    if (t == 0) { cbs = -1; above_s = 0; }
    __syncthreads();
    for (int off = 1; off < 1024; off <<= 1) {
        u32 add = (t + off < 1024) ? suf[t + off] : 0u;
        __syncthreads();
        suf[t] += add;
        __syncthreads();
    }
    u32 st = suf[t];
    u32 stn = (t < 1023) ? suf[t + 1] : 0u;
    if (st >= (u32)K_TOP && stn < (u32)K_TOP) {       // at most one thread
        cbs = t;
        above_s = stn;                                 // sum of chunks above cb
    }
    __syncthreads();
    int cb = cbs;
    if (t < 64) {                                      // wave 0 does the fine pass
        u32 thresh = 0;
        if (cb >= 0) {
            u32 above = above_s;
            u32 v = (t < 16) ? hist[cb * 16 + t] : 0u;
            for (int off = 1; off < 64; off <<= 1) {
                u32 o = __shfl_down(v, off);
                if (t + off < 64) v += o;
            }
            u64 bal = __ballot(v + above >= (u32)K_TOP);
            int bstar = 63 - __builtin_clzll((unsigned long long)bal);
            thresh = ((u32)(cb * 16 + bstar)) << 16;
        }
        if (t == 0) meta[1] = thresh;                  // meta[0] zeroed by zero_kernel
    }
}

// ---------------- kernel 3: compact candidates above threshold ----------------
__global__ __launch_bounds__(256) void compact_kernel(const u64* __restrict__ keys,
        u32* __restrict__ meta, u64* __restrict__ comp) {
    __shared__ u32 woff[4];
    __shared__ u32 bbase;
    int i = blockIdx.x * 256 + threadIdx.x;
    int wid = threadIdx.x >> 6, lane = threadIdx.x & 63;
    u64 key = (i < NA) ? keys[i] : 0ull;
    u32 sb = (u32)(key >> 32);
    u32 th = meta[1];
    bool take = (i < NA) && (sb != 0u) && (sb >= th);
    u64 bal = __ballot(take);
    if (lane == 0) woff[wid] = (u32)__popcll(bal);
    __syncthreads();
    if (threadIdx.x == 0) {
        u32 t0 = woff[0], t1 = woff[1], t2 = woff[2], t3 = woff[3];
        bbase = atomicAdd(&meta[0], t0 + t1 + t2 + t3);
        woff[0] = 0; woff[1] = t0; woff[2] = t0 + t1; woff[3] = t0 + t1 + t2;
    }
    __syncthreads();
    if (take) {
        u32 pos = bbase + woff[wid] + (u32)__popcll(bal & ((1ull << lane) - 1ull));
        if (pos < CAP) comp[pos] = key;
    }
}

// ---------------- kernel 4a: 2-D partial rank-by-counting ----------------
__global__ __launch_bounds__(256) void rank_partial_kernel(const u64* __restrict__ comp,
        const u32* __restrict__ meta, u32* __restrict__ rankArr) {
    __shared__ u64 tile[1024];
    u32 cnt = meta[0];
    int n = (int)(cnt < (u32)CAP ? cnt : (u32)CAP);
    int i0 = blockIdx.x * 256;
    int j0 = blockIdx.y * 1024;
    if (i0 >= n || j0 >= n) return;                  // uniform early exit
    int lim = n - j0; if (lim > 1024) lim = 1024;
    for (int k = threadIdx.x; k < 1024; k += 256)
        tile[k] = (k < lim) ? comp[j0 + k] : 0ull;
    __syncthreads();
    int i = i0 + threadIdx.x;
    if (i < n) {
        u64 key = comp[i];
        u32 r = 0;
#pragma unroll 8
        for (int j = 0; j < 1024; ++j) r += (tile[j] > key) ? 1u : 0u;
        atomicAdd(&rankArr[i], r);
    }
}

// ---------------- kernel 4b: scatter keys to their rank ----------------
__global__ __launch_bounds__(256) void scatter_kernel(const u64* __restrict__ comp,
        const u32* __restrict__ meta, const u32* __restrict__ rankArr,
        u64* __restrict__ sorted) {
    u32 cnt = meta[0];
    int n = (int)(cnt < (u32)CAP ? cnt : (u32)CAP);
    int i = blockIdx.x * 256 + threadIdx.x;
    if (i < n) {
        u32 r = rankArr[i];
        if (r < (u32)K_TOP) sorted[r] = comp[i];     // keys unique -> permutation
    }
}

// ---------------- kernel 5: wave-per-anchor gather of boxes/classes/scores ---------
__global__ __launch_bounds__(256) void gather_kernel(const u64* __restrict__ sorted,
        const float* __restrict__ preds, float* __restrict__ boxes,
        float* __restrict__ scores, float* __restrict__ classes,
        float* __restrict__ areas) {
#pragma clang fp contract(off)
    int lane = threadIdx.x & 63;
    int i = blockIdx.x * 4 + (threadIdx.x >> 6);     // i in [0, 8192)
    u64 key = sorted[i];
    u32 sb = (u32)(key >> 32);
    float score = __uint_as_float(sb);
    if (score > 0.0f) {                               // uniform across the wave
        u32 idx = ~(u32)(key & 0xffffffffull);
        const float* p = preds + (size_t)idx * ROWLEN;
        float v0 = p[lane];
        float v1 = (lane < ROWLEN - 64) ? p[64 + lane] : 0.0f;
        float obj = __shfl(v0, 4);
        u64 kb = 0;
        if (lane >= 5) {
            float q = v0 * obj;                       // class lane-5
            kb = ((u64)__float_as_uint(q) << 8) | (u32)(255 - (lane - 5));
        }
        if (lane < 21) {
            float q = v1 * obj;                       // class 59+lane
            u64 kb2 = ((u64)__float_as_uint(q) << 8) | (u32)(255 - (59 + lane));
            if (kb2 > kb) kb = kb2;
        }
        for (int off = 32; off; off >>= 1) {
            u64 o = __shfl_xor(kb, off);
            if (o > kb) kb = o;
        }
        u32 cls = 255u - (u32)(kb & 0xffull);
        float x = __shfl(v0, 0), y = __shfl(v0, 1);
        float w = __shfl(v0, 2), h = __shfl(v0, 3);
        if (lane == 0) {
            float ymin = y - h * 0.5f, xmin = x - w * 0.5f;
            float ymax = y + h * 0.5f, xmax = x + w * 0.5f;
            boxes[i * 4 + 0] = ymin;
            boxes[i * 4 + 1] = xmin;
            boxes[i * 4 + 2] = ymax;
            boxes[i * 4 + 3] = xmax;
            scores[i] = score;
            classes[i] = (float)cls;
            areas[i] = (ymax - ymin) * (xmax - xmin);
        }
    } else if (lane == 0) {
        boxes[i * 4 + 0] = 0.0f; boxes[i * 4 + 1] = 0.0f;
        boxes[i * 4 + 2] = 0.0f; boxes[i * 4 + 3] = 0.0f;
        scores[i] = 0.0f;
        classes[i] = 0.0f;
        areas[i] = 0.0f;
    }
}

// ---------------- kernel 6: full suppression bitmask (iou > thres, j > i) ----------
// Round-5 structure (passed, absmax 0): lane=row, column operands via LDS
// broadcast reads, divide replaced bit-exactly by f64 multiply-compare, valid
// fused in, below-diag blocks skipped. Unchanged this round.
__global__ __launch_bounds__(256) void mask_kernel(const float* __restrict__ boxes,
        const float* __restrict__ areas, const float* __restrict__ scores,
        u64* __restrict__ mask, u64* __restrict__ remw) {
#pragma clang fp contract(off)
    int cx = blockIdx.x;                 // col tile: 256 cols = words [cx*4, cx*4+4)
    int ry = blockIdx.y;                 // row tile: rows [ry*64, ry*64+64)
    if (cx < (ry >> 2)) return;          // fully below diagonal: never read
    __shared__ float4 cb[256];           // column boxes
    __shared__ float  ca[256];           // column areas
    __shared__ u64 st[64 * 5];           // [row][word], stride 5 (bank spread)
    int tid = threadIdx.x;
    int wv = tid >> 6, lane = tid & 63;
    int r0 = ry * 64;
    int jw = cx * 4 + wv;                // this wave's column word
    cb[tid] = ((const float4*)boxes)[cx * 256 + tid];   // coalesced col stage
    ca[tid] = areas[cx * 256 + tid];
    if (cx == (ry >> 2) && wv == 0) {    // fused valid: remw[ry]
        u64 b = __ballot(scores[r0 + lane] > 0.0f);
        if (lane == 0) remw[ry] = b;
    }
    __syncthreads();
    u64 myword = 0;
    if (jw >= ry) {                      // below-diag waves: zeros
        float4 bi = ((const float4*)boxes)[r0 + lane];  // this lane's ROW (coalesced)
        float ai = areas[r0 + lane];
        const double Bd = (double)IOU_THRES + 0x1p-26;  // fl32(x)>T <=> x>Bd
        int kb = wv * 64;
#pragma unroll
        for (int k = 0; k < 64; ++k) {
            float4 bj = cb[kb + k];      // all lanes same addr -> LDS broadcast
            float aj = ca[kb + k];
            float ty = fmaxf(bi.x, bj.x);
            float tx = fmaxf(bi.y, bj.y);
            float by = fminf(bi.z, bj.z);
            float bx = fminf(bi.w, bj.w);
            float inter = fmaxf(by - ty, 0.0f) * fmaxf(bx - tx, 0.0f);
            float uni = (ai + aj) - inter;
            float u = uni + 1e-9f;
            bool sup = ((double)inter > Bd * (double)u); // exact == fl32 div > T
            myword |= sup ? (1ull << k) : 0ull;          // k compile-time const
        }
        if (jw == ry)                    // diag word: keep cols j > row only
            myword &= (lane < 63) ? (~0ull << (lane + 1)) : 0ull;
    }
    st[lane * 5 + wv] = myword;          // transpose through LDS for coalesced flush
    __syncthreads();
    mask[(size_t)(r0 + (tid >> 2)) * 128 + cx * 4 + (tid & 3)] =
            st[(tid >> 2) * 5 + (tid & 3)];
}

// ---------------- kernel 7: pipelined greedy scan (4 waves, double-buffered) -------
// Round-6 rewrite: wave 0 runs the (inherently serial) pop chain on window w
// while waves 1-3 stage window w+1 into the other LDS buffer; the per-window
// fold of all keeps-so-far is parallelized over all 256 threads and combined
// via accW[4][8]. Pop-chain algebra byte-identical to the single-wave version.
__device__ __forceinline__ u64 rfl64(u64 v) {
    u32 lo = (u32)__builtin_amdgcn_readfirstlane((int)(u32)v);
    u32 hi = (u32)__builtin_amdgcn_readfirstlane((int)(u32)(v >> 32));
    return ((u64)hi << 32) | lo;
}

__device__ __forceinline__ u64 bcast64(u64 v, int srclane) {
    u32 lo = (u32)__builtin_amdgcn_readlane((int)(u32)v, srclane);
    u32 hi = (u32)__builtin_amdgcn_readlane((int)(u32)(v >> 32), srclane);
    return ((u64)hi << 32) | lo;
}

__device__ __forceinline__ u64 shfl_xor64(u64 v, int m) {
    u32 lo = __shfl_xor((u32)v, m, 64);
    u32 hi = __shfl_xor((u32)(v >> 32), m, 64);
    return ((u64)hi << 32) | lo;
}

__global__ __launch_bounds__(256) void nms_scan_kernel(const u64* __restrict__ mask,
        const u64* __restrict__ remw, const float* __restrict__ boxes,
        const float* __restrict__ scores, const float* __restrict__ classes,
        float* __restrict__ out) {
    __shared__ u64 sub[2][WIN * SSTR];                // 2 x 36 KB double buffer
    __shared__ u64 accW[4][8];                        // per-wave fold partials
    __shared__ u32 ki[MAX_DET + 8];                   // kept indices (ascending)
    __shared__ int n_sh;
    int tid = threadIdx.x;
    int wid = tid >> 6, lane = tid & 63;
    if (tid == 0) n_sh = 0;
    // stage window 0 into buf 0 (all 256 threads, coalesced uint4)
#pragma unroll
    for (int it = 0; it < 8; ++it) {
        int idx = it * 256 + tid;                     // 2048 uint4
        int r = idx >> 2, j = (idx & 3) * 2;
        uint4 v = *(const uint4*)&mask[(size_t)r * 128 + j];
        sub[0][r * SSTR + j]     = ((u64)v.y << 32) | v.x;
        sub[0][r * SSTR + j + 1] = ((u64)v.w << 32) | v.z;
    }
    __syncthreads();
    int n = 0;
    for (int win = 0; win < NWIN; ++win) {
        if (n >= MAX_DET) break;                      // uniform
        int rbase = win * WIN;
        int cb = win & 1;
        // ---- parallel fold of keeps from earlier windows (all 4 waves) ----
        u64 acc[8] = {0, 0, 0, 0, 0, 0, 0, 0};
        for (int m = tid; m < n; m += 256) {
            int k = (int)ki[m];
            const u64* rp = &mask[(size_t)k * 128 + win * 8];
#pragma unroll
            for (int j = 0; j < 8; ++j) acc[j] |= rp[j];
        }
#pragma unroll
        for (int j = 0; j < 8; ++j)
            for (int off = 32; off; off >>= 1) acc[j] |= shfl_xor64(acc[j], off);
        if (lane == 0) {
#pragma unroll
            for (int j = 0; j < 8; ++j) accW[wid][j] = acc[j];
        }
        __syncthreads();
        if (wid != 0) {
            // ---- helper waves: stage NEXT window into the other buffer ----
            if (win + 1 < NWIN) {
                int t = tid - 64;                     // 0..191
                for (int it = 0; it < 11; ++it) {
                    int idx = it * 192 + t;
                    if (idx < 2048) {
                        int r = idx >> 2, j = (idx & 3) * 2;
                        uint4 v = *(const uint4*)&mask[
                                (size_t)(rbase + WIN + r) * 128 + (win + 1) * 8 + j];
                        sub[cb ^ 1][r * SSTR + j]     = ((u64)v.y << 32) | v.x;
                        sub[cb ^ 1][r * SSTR + j + 1] = ((u64)v.w << 32) | v.z;
                    }
                }
            }
        } else {
            // ---- wave 0: pop chain on current buffer ----
            u64 diag[8];
#pragma unroll
            for (int sw = 0; sw < 8; ++sw)
                diag[sw] = sub[cb][(sw * 64 + lane) * SSTR + sw];
            int n0 = n;
            u64 keptW[8] = {0, 0, 0, 0, 0, 0, 0, 0};
#pragma unroll
            for (int sw = 0; sw < 8; ++sw) {
                if (n < MAX_DET) {
                    u64 acc2 = 0;
#pragma unroll
                    for (int wp = 0; wp < 8; ++wp) {
                        if (wp < sw) {
                            if ((keptW[wp] >> lane) & 1ull)
                                acc2 |= sub[cb][(wp * 64 + lane) * SSTR + sw];
                        }
                    }
                    for (int off = 32; off; off >>= 1) acc2 |= shfl_xor64(acc2, off);
                    u64 afold = accW[0][sw] | accW[1][sw] | accW[2][sw] | accW[3][sw];
                    u64 cur = rfl64(remw[win * 8 + sw]) & ~rfl64(afold) & ~rfl64(acc2);
                    u64 kw = 0;
                    while (cur != 0ull && n < MAX_DET) {  // uniform scalar pop chain
                        int b = __ffsll((unsigned long long)cur) - 1;
                        u64 slice = bcast64(diag[sw], b); // row (sw*64+b), word sw
                        kw |= (1ull << b);
                        cur &= ~(slice | (1ull << b));
                        ++n;
                    }
                    keptW[sw] = kw;
                }
            }
            // append kept indices (ascending index = greedy order)
            int base = n0;
#pragma unroll
            for (int sw = 0; sw < 8; ++sw) {
                u64 kw = keptW[sw];
                if ((kw >> lane) & 1ull) {
                    int rr = (int)__popcll(kw & ((1ull << lane) - 1ull));
                    ki[base + rr] = (u32)(rbase + sw * 64 + lane);
                }
                base += (int)__popcll(kw);
            }
            if (lane == 0) n_sh = n;
        }
        __syncthreads();                              // staging + pop + ki complete
        n = n_sh;
    }
    __syncthreads();
    // ---- parallel output phase: 256 threads over MAX_DET detections ----
    for (int m = tid; m < MAX_DET; m += 256) {
        float4 b = make_float4(0.0f, 0.0f, 0.0f, 0.0f);
        float c = 0.0f, s = 0.0f;
        if (m < n) {
            int k = (int)ki[m];
            b = ((const float4*)boxes)[k];
            c = classes[k];
            s = scores[k];
        }
        ((float4*)out)[m] = b;
        out[1200 + m] = c;
        out[1500 + m] = s;
    }
}

// ---------------- launch ----------------
extern "C" void kernel_launch(void* const* d_in, const int* in_sizes, int n_in,
                              void* d_out, int out_size, void* d_ws, size_t ws_size,
                              hipStream_t stream) {
    const float* preds = (const float*)d_in[0];
    char* ws = (char*)d_ws;

    // ws layout (bytes), total 9991104:
    //   [0, 65536)             sumhist     u32[16384]
    //   [65536, 196096)        rankArr     u32[32640] (own region: zeroed up-front)
    //   [262144, 262208)       meta        u32[16]   ([0]=counter, [1]=thresh)
    //   [262208, 263232)       remw        u64[128]
    //   [263232, 328768)       sorted      u64[8192]
    //   [328768, 1144768)      keys        u64[102000] (dead after compact)
    //   [1144768, 1405888)     comp        u64[32640] (dead after scatter;
    //                                      front 32768 B reused as careas)
    //   [1405888, 1536960)     top_boxes   f32[8192*4]
    //   [1536960, 1569728)     top_scores  f32[8192]
    //   [1569728, 1602496)     top_classes f32[8192]
    //   [1602496, 9991104)     mask        u64[8192*128]  (8 MB; front 512 KiB
    //                                      doubles as 8x16384 hist planes earlier)
    u32*   sumhist = (u32*)(ws + 0);
    u32*   rankArr = (u32*)(ws + 65536);
    u32*   meta    = (u32*)(ws + 262144);
    u64*   remw    = (u64*)(ws + 262208);
    u64*   sorted  = (u64*)(ws + 263232);
    u64*   keys    = (u64*)(ws + 328768);
    u64*   comp    = (u64*)(ws + 1144768);
    float* careas  = (float*)(ws + 1144768);         // aliases comp (dead by gather)
    float* tboxes  = (float*)(ws + 1405888);
    float* tscores = (float*)(ws + 1536960);
    float* tclass  = (float*)(ws + 1569728);
    u64*   mask    = (u64*)(ws + 1602496);
    u32*   histP   = (u32*)(ws + 1602496);           // aliases mask region (earlier)
    float* out     = (float*)d_out;

    zero_kernel<<<128, 256, 0, stream>>>((uint4*)(ws + 262144), (uint4*)rankArr,
            (uint4*)histP);
    score_key_kernel<<<(NA + 3) / 4, 256, 0, stream>>>(preds, keys, histP);
    reduce_hist_kernel<<<64, 256, 0, stream>>>(histP, sumhist);
    cutoff_kernel<<<1, 1024, 0, stream>>>(sumhist, meta);
    compact_kernel<<<(NA + 255) / 256, 256, 0, stream>>>(keys, meta, comp);
    rank_partial_kernel<<<dim3((CAP + 255) / 256, (CAP + 1023) / 1024), 256, 0, stream>>>(
            comp, meta, rankArr);
    scatter_kernel<<<(CAP + 255) / 256, 256, 0, stream>>>(comp, meta, rankArr, sorted);
    gather_kernel<<<K_TOP / 4, 256, 0, stream>>>(sorted, preds, tboxes, tscores,
            tclass, careas);
    mask_kernel<<<dim3(32, 128), 256, 0, stream>>>(tboxes, careas, tscores, mask, remw);
    nms_scan_kernel<<<1, 256, 0, stream>>>(mask, remw, tboxes, tscores, tclass, out);
}